// Round 5
// baseline (566.903 us; speedup 1.0000x reference)
//
#include <hip/hip_runtime.h>

typedef unsigned short u16;
typedef unsigned int u32;
typedef float f32x4 __attribute__((ext_vector_type(4)));
typedef short i16x8 __attribute__((ext_vector_type(8)));
typedef __bf16 bf16x8_t __attribute__((ext_vector_type(8)));

#define LQ 43054

__device__ __forceinline__ float bf2f(u16 u) {
  union { u32 i; float f; } v; v.i = ((u32)u) << 16; return v.f;
}
__device__ __forceinline__ u16 f2bf(float f) {
  u32 i = __float_as_uint(f);
  return (u16)((i + 0x7FFFu + ((i >> 16) & 1u)) >> 16);
}

// ---- MFMA wrapper robust to builtin operand type (V8 short vs V8 __bf16) ----
template <typename T>
__device__ __forceinline__ auto mfma_try(T a, T b, f32x4 c, int)
    -> decltype(__builtin_amdgcn_mfma_f32_16x16x32_bf16(a, b, c, 0, 0, 0)) {
  return __builtin_amdgcn_mfma_f32_16x16x32_bf16(a, b, c, 0, 0, 0);
}
template <typename T>
__device__ __forceinline__ f32x4 mfma_try(T a, T b, f32x4 c, long) {
  return __builtin_amdgcn_mfma_f32_16x16x32_bf16(
      __builtin_bit_cast(bf16x8_t, a), __builtin_bit_cast(bf16x8_t, b), c, 0, 0, 0);
}
__device__ __forceinline__ f32x4 mfma_bf16(i16x8 a, i16x8 b, f32x4 c) {
  return mfma_try(a, b, c, 0);
}

// ---- all 6 weight transposes in one kernel: f32 (256 x N) -> bf16 (N x 256) ----
__global__ void transpose_all_kernel(
    const float* __restrict__ w_off, const float* __restrict__ w_attn,
    const float* __restrict__ w_val, const float* __restrict__ w_out,
    const float* __restrict__ w1, const float* __restrict__ w2,
    u16* __restrict__ wT) {
  int b = blockIdx.x;
  const float* src; u16* dst; int N; int col;
  if (b < 256)       { src = w_off;  dst = wT;          N = 256; col = b; }
  else if (b < 384)  { src = w_attn; dst = wT + 65536;  N = 128; col = b - 256; }
  else if (b < 640)  { src = w_val;  dst = wT + 98304;  N = 256; col = b - 384; }
  else if (b < 896)  { src = w_out;  dst = wT + 163840; N = 256; col = b - 640; }
  else if (b < 1152) { src = w1;     dst = wT + 229376; N = 256; col = b - 896; }
  else               { src = w2;     dst = wT + 294912; N = 256; col = b - 1152; }
  dst[col * 256 + threadIdx.x] = f2bf(src[threadIdx.x * N + col]);
}

// ================= shared A-staging helpers (64 rows x 256 bf16, 32 KiB) ====
// bf16 source
__device__ __forceinline__ void stage_a_bf16(uint4* As, const u16* A, int r0, int M, int tid) {
#pragma unroll
  for (int it = 0; it < 8; ++it) {
    int e = tid + it * 256;
    int row = e >> 5, c = e & 31;
    int gr = r0 + row;
    uint4 v = make_uint4(0u, 0u, 0u, 0u);
    if (gr < M) v = ((const uint4*)A)[gr * 32 + c];
    As[row * 32 + (c ^ (row & 7))] = v;
  }
}
// f32 source (optionally + f32 addend), converted to bf16
template <int ADD>
__device__ __forceinline__ void stage_a_f32(uint4* As, const float* A, const float* A2,
                                            int r0, int M, int tid) {
#pragma unroll
  for (int it = 0; it < 16; ++it) {
    int e = tid + it * 256;
    int row = e >> 6, c4 = e & 63;
    int gr = r0 + row;
    float4 v = make_float4(0.f, 0.f, 0.f, 0.f);
    if (gr < M) {
      v = ((const float4*)A)[gr * 64 + c4];
      if constexpr (ADD) {
        float4 p = ((const float4*)A2)[gr * 64 + c4];
        v.x += p.x; v.y += p.y; v.z += p.z; v.w += p.w;
      }
    }
    uint2 pk;
    pk.x = (u32)f2bf(v.x) | ((u32)f2bf(v.y) << 16);
    pk.y = (u32)f2bf(v.z) | ((u32)f2bf(v.w) << 16);
    int c = c4 >> 1, hf = c4 & 1;
    ((uint2*)As)[((row * 32 + (c ^ (row & 7))) << 1) | hf] = pk;
  }
}

// ---- generic GEMM: C[M x N] = A[M x 256] * Bt[N x 256]^T + bias ----
// B-fragments are loaded straight from global (L2-resident 128 KB weights);
// no Bs LDS, no barriers after the single A-stage barrier.
// AIN: 0 = A f32, 2 = A bf16.  MODE: 1 = bf16, 2 = relu+bf16.  NT = N/64.
template <int AIN, int MODE, int NT>
__global__ __launch_bounds__(256, 4) void gemm_kernel(
    const void* __restrict__ Av, const u16* __restrict__ Bt,
    const float* __restrict__ bias, void* __restrict__ out, int M) {
  constexpr int N = NT * 64;
  __shared__ uint4 As[2048];
  const int tid = threadIdx.x;
  const int w = tid >> 6, lane = tid & 63, quad = lane >> 4, l16 = lane & 15;
  const int r0 = blockIdx.x * 64;
  if constexpr (AIN == 2) stage_a_bf16(As, (const u16*)Av, r0, M, tid);
  else                    stage_a_f32<0>(As, (const float*)Av, nullptr, r0, M, tid);
  __syncthreads();
  const int arow = w * 16 + l16;
  i16x8 afr[8];
#pragma unroll
  for (int kk = 0; kk < 8; ++kk)
    afr[kk] = __builtin_bit_cast(i16x8, As[arow * 32 + (((kk << 2) + quad) ^ (arow & 7))]);
  const int baserow = r0 + w * 16 + (quad << 2);
#pragma unroll
  for (int t = 0; t < NT * 4; ++t) {
    const uint4* bp = (const uint4*)Bt + (t * 16 + l16) * 32 + quad;
    i16x8 bfr[8];
#pragma unroll
    for (int kk = 0; kk < 8; ++kk) bfr[kk] = __builtin_bit_cast(i16x8, bp[kk << 2]);
    f32x4 acc = {0.f, 0.f, 0.f, 0.f};
#pragma unroll
    for (int kk = 0; kk < 8; ++kk) acc = mfma_bf16(afr[kk], bfr[kk], acc);
    const int col = t * 16 + l16;
    const float bv = bias[col];
#pragma unroll
    for (int r = 0; r < 4; ++r) {
      int grow = baserow + r;
      if (grow < M) {
        float val = acc[r] + bv;
        if (MODE == 1) ((u16*)out)[grow * N + col] = f2bf(val);
        else           ((u16*)out)[grow * N + col] = f2bf(fmaxf(val, 0.f));
      }
    }
  }
}

// ---- fused offsets + attention-softmax GEMM: A = bf16(query + pos) ----
// Bt has 384 rows (w_offT then w_attnT contiguous). tiles 0..15 -> offb bf16;
// tiles 16..23 -> per-head softmax (16 cols in the 16 l16 lanes) -> aw f32.
__global__ __launch_bounds__(256, 4) void offaw_gemm_kernel(
    const float* __restrict__ query, const float* __restrict__ pos,
    const u16* __restrict__ Bt, const float* __restrict__ b_off,
    const float* __restrict__ b_attn, u16* __restrict__ offb,
    float* __restrict__ aw, int M) {
  __shared__ uint4 As[2048];
  const int tid = threadIdx.x;
  const int w = tid >> 6, lane = tid & 63, quad = lane >> 4, l16 = lane & 15;
  const int r0 = blockIdx.x * 64;
  stage_a_f32<1>(As, query, pos, r0, M, tid);
  __syncthreads();
  const int arow = w * 16 + l16;
  i16x8 afr[8];
#pragma unroll
  for (int kk = 0; kk < 8; ++kk)
    afr[kk] = __builtin_bit_cast(i16x8, As[arow * 32 + (((kk << 2) + quad) ^ (arow & 7))]);
  const int baserow = r0 + w * 16 + (quad << 2);
#pragma unroll
  for (int t = 0; t < 24; ++t) {
    const uint4* bp = (const uint4*)Bt + (t * 16 + l16) * 32 + quad;
    i16x8 bfr[8];
#pragma unroll
    for (int kk = 0; kk < 8; ++kk) bfr[kk] = __builtin_bit_cast(i16x8, bp[kk << 2]);
    f32x4 acc = {0.f, 0.f, 0.f, 0.f};
#pragma unroll
    for (int kk = 0; kk < 8; ++kk) acc = mfma_bf16(afr[kk], bfr[kk], acc);
    if (t < 16) {
      const int col = t * 16 + l16;
      const float bv = b_off[col];
#pragma unroll
      for (int r = 0; r < 4; ++r) {
        int grow = baserow + r;
        if (grow < M) ((u16*)offb)[grow * 256 + col] = f2bf(acc[r] + bv);
      }
    } else {
      const int colc = (t - 16) * 16 + l16;
      const float bv = b_attn[colc];
#pragma unroll
      for (int r = 0; r < 4; ++r) {
        float v = acc[r] + bv;
        float m = v;
#pragma unroll
        for (int o = 1; o < 16; o <<= 1) m = fmaxf(m, __shfl_xor(m, o));
        float e = __expf(v - m);
        float s = e;
#pragma unroll
        for (int o = 1; o < 16; o <<= 1) s += __shfl_xor(s, o);
        int grow = baserow + r;
        if (grow < M) aw[grow * 128 + colc] = e / s;
      }
    }
  }
}

// ---- GEMM + residual + LayerNorm fused epilogue (full 256-col rows/block) ----
// RBF: resid bf16 if 1 else f32.  OBF: out bf16 if 1 else f32.
template <int RBF, int OBF>
__global__ __launch_bounds__(256, 3) void gemm_ln_kernel(
    const u16* __restrict__ A, const u16* __restrict__ Bt,
    const float* __restrict__ bias, const void* __restrict__ residv,
    const float* __restrict__ g, const float* __restrict__ beta,
    void* __restrict__ outv, int M) {
  __shared__ uint4 As[2048];
  const int tid = threadIdx.x;
  const int w = tid >> 6, lane = tid & 63, quad = lane >> 4, l16 = lane & 15;
  const int r0 = blockIdx.x * 64;
  stage_a_bf16(As, A, r0, M, tid);
  __syncthreads();
  const int arow = w * 16 + l16;
  i16x8 afr[8];
#pragma unroll
  for (int kk = 0; kk < 8; ++kk)
    afr[kk] = __builtin_bit_cast(i16x8, As[arow * 32 + (((kk << 2) + quad) ^ (arow & 7))]);
  const int baserow = r0 + w * 16 + (quad << 2);
  f32x4 vals[16];
  float s[4] = {0.f, 0.f, 0.f, 0.f}, s2[4] = {0.f, 0.f, 0.f, 0.f};
#pragma unroll
  for (int t = 0; t < 16; ++t) {
    const uint4* bp = (const uint4*)Bt + (t * 16 + l16) * 32 + quad;
    i16x8 bfr[8];
#pragma unroll
    for (int kk = 0; kk < 8; ++kk) bfr[kk] = __builtin_bit_cast(i16x8, bp[kk << 2]);
    f32x4 acc = {0.f, 0.f, 0.f, 0.f};
#pragma unroll
    for (int kk = 0; kk < 8; ++kk) acc = mfma_bf16(afr[kk], bfr[kk], acc);
    const int col = t * 16 + l16;
    const float bv = bias[col];
#pragma unroll
    for (int r = 0; r < 4; ++r) {
      int row = baserow + r;
      float rv = 0.f;
      if (row < M) rv = RBF ? bf2f(((const u16*)residv)[row * 256 + col])
                            : ((const float*)residv)[row * 256 + col];
      float val = acc[r] + bv + rv;
      vals[t][r] = val;
      s[r] += val; s2[r] += val * val;
    }
  }
#pragma unroll
  for (int r = 0; r < 4; ++r)
#pragma unroll
    for (int o = 1; o < 16; o <<= 1) {
      s[r] += __shfl_xor(s[r], o);
      s2[r] += __shfl_xor(s2[r], o);
    }
  float mr[4], ir[4];
#pragma unroll
  for (int r = 0; r < 4; ++r) {
    mr[r] = s[r] * (1.f / 256.f);
    float var = s2[r] * (1.f / 256.f) - mr[r] * mr[r];
    ir[r] = rsqrtf(var + 1e-5f);
  }
#pragma unroll
  for (int t = 0; t < 16; ++t) {
    const int col = t * 16 + l16;
    const float gv = g[col], bev = beta[col];
#pragma unroll
    for (int r = 0; r < 4; ++r) {
      int row = baserow + r;
      if (row < M) {
        float o = (vals[t][r] - mr[r]) * ir[r] * gv + bev;
        if (OBF) ((u16*)outv)[row * 256 + col] = f2bf(o);
        else     ((float*)outv)[row * 256 + col] = o;
      }
    }
  }
}

// ---- fused prep + deformable sampling: one block = 2 queries ----
__global__ __launch_bounds__(256) void sampler_kernel(
    const float* __restrict__ refp,  // Lq x 4 x 2 (f32)
    const u16* __restrict__ offb,    // Lq x 256 (bf16 offsets)
    const float* __restrict__ aw,    // Lq x 128 (f32, softmaxed)
    const u16* __restrict__ value,   // Lq x 256 (bf16)
    u32* __restrict__ accv) {        // Lq x 128 u32 (bf16 channel pairs)
  __shared__ uint4 rec[272];         // slot = qs*136 + h*17 + p (bank-padded)
  const int t = threadIdx.x;
  const int b = blockIdx.x;
  {
    const int qs = t >> 7, j = t & 127;
    const int i = b * 2 + qs;
    const int h = j >> 4, lp = j & 15, l = lp >> 2;
    const int Wl = (l == 0) ? 180 : (l == 1) ? 90 : (l == 2) ? 45 : 23;
    const int st = (l == 0) ? 0 : (l == 1) ? 32400 : (l == 2) ? 40500 : 42525;
    const float wj = aw[i * 128 + j];
    const u32 o2 = *(const u32*)(offb + i * 256 + h * 32 + lp * 2);
    const float ox = bf2f((u16)(o2 & 0xffffu)), oy = bf2f((u16)(o2 >> 16));
    const float rx = refp[i * 8 + l * 2], ry = refp[i * 8 + l * 2 + 1];
    float x = rx * (float)Wl + ox - 0.5f;
    float y = ry * (float)Wl + oy - 0.5f;
    float x0f = floorf(x), y0f = floorf(y);
    float fx = x - x0f, fy = y - y0f;
    int x0 = (int)x0f, y0 = (int)y0f;
    bool vx0 = (x0 >= 0) & (x0 < Wl), vx1 = (x0 + 1 >= 0) & (x0 + 1 < Wl);
    bool vy0 = (y0 >= 0) & (y0 < Wl), vy1 = (y0 + 1 >= 0) & (y0 + 1 < Wl);
    int x0c = min(max(x0, 0), Wl - 1), x1c = min(max(x0 + 1, 0), Wl - 1);
    int y0c = min(max(y0, 0), Wl - 1), y1c = min(max(y0 + 1, 0), Wl - 1);
    float w00 = (vx0 & vy0) ? wj * (1.f - fx) * (1.f - fy) : 0.f;
    float w01 = (vx1 & vy0) ? wj * fx * (1.f - fy) : 0.f;
    float w10 = (vx0 & vy1) ? wj * (1.f - fx) * fy : 0.f;
    float w11 = (vx1 & vy1) ? wj * fx * fy : 0.f;
    uint4 r;
    r.x = (u32)((st + y0c * Wl + x0c) * 512 + h * 64) | (u32)(x1c - x0c);
    r.y = (u32)(y1c - y0c) * (u32)(Wl * 512);
    r.z = (u32)f2bf(w00) | ((u32)f2bf(w01) << 16);
    r.w = (u32)f2bf(w10) | ((u32)f2bf(w11) << 16);
    rec[qs * 136 + h * 17 + lp] = r;
  }
  __syncthreads();
  const int qs = t >> 7, j = t & 127;
  const int h = j >> 4, dp = j & 15;
  const char* vb = (const char*)value;
  float a0 = 0.f, a1 = 0.f;
  const int rbase = qs * 136 + h * 17;
#pragma unroll
  for (int p = 0; p < 16; ++p) {
    uint4 r = rec[rbase + p];
    u32 base = (r.x & 0xFFFFFFFEu) + (u32)(dp * 4);
    u32 dxo = (r.x & 1u) << 9;
    u32 dyo = r.y;
    float w00 = __uint_as_float(r.z << 16);
    float w01 = __uint_as_float(r.z & 0xFFFF0000u);
    float w10 = __uint_as_float(r.w << 16);
    float w11 = __uint_as_float(r.w & 0xFFFF0000u);
    u32 p00 = *(const u32*)(vb + base);
    u32 p01 = *(const u32*)(vb + base + dxo);
    u32 p10 = *(const u32*)(vb + base + dyo);
    u32 p11 = *(const u32*)(vb + base + dyo + dxo);
    a0 = fmaf(w00, __uint_as_float(p00 << 16), a0);
    a1 = fmaf(w00, __uint_as_float(p00 & 0xFFFF0000u), a1);
    a0 = fmaf(w01, __uint_as_float(p01 << 16), a0);
    a1 = fmaf(w01, __uint_as_float(p01 & 0xFFFF0000u), a1);
    a0 = fmaf(w10, __uint_as_float(p10 << 16), a0);
    a1 = fmaf(w10, __uint_as_float(p10 & 0xFFFF0000u), a1);
    a0 = fmaf(w11, __uint_as_float(p11 << 16), a0);
    a1 = fmaf(w11, __uint_as_float(p11 & 0xFFFF0000u), a1);
  }
  u32 pk = (u32)f2bf(a0) | ((u32)f2bf(a1) << 16);
  accv[(b * 2 + qs) * 128 + j] = pk;
}

extern "C" void kernel_launch(void* const* d_in, const int* in_sizes, int n_in,
                              void* d_out, int out_size, void* d_ws, size_t ws_size,
                              hipStream_t stream) {
  const float* query  = (const float*)d_in[0];
  const float* refp   = (const float*)d_in[1];
  const float* pos    = (const float*)d_in[2];
  const float* w_off  = (const float*)d_in[5];
  const float* b_off  = (const float*)d_in[6];
  const float* w_attn = (const float*)d_in[7];
  const float* b_attn = (const float*)d_in[8];
  const float* w_val  = (const float*)d_in[9];
  const float* b_val  = (const float*)d_in[10];
  const float* w_out  = (const float*)d_in[11];
  const float* b_out  = (const float*)d_in[12];
  const float* g1     = (const float*)d_in[13];
  const float* beta1  = (const float*)d_in[14];
  const float* w1     = (const float*)d_in[15];
  const float* b1     = (const float*)d_in[16];
  const float* w2     = (const float*)d_in[17];
  const float* b2     = (const float*)d_in[18];
  const float* g2     = (const float*)d_in[19];
  const float* beta2  = (const float*)d_in[20];

  char* ws = (char*)d_ws;
  // layout (byte offsets). Peak 88.9 MiB.
  u16*   wT    = (u16*)(ws + 0);            //   720,896, live whole launch
  u16*   value = (u16*)(ws + 720896);       // 22,043,648  dead after sampler
  u16*   offb  = (u16*)(ws + 22764544);     // 22,043,648  dead after sampler
  float* aw    = (float*)(ws + 44808192);   // 22,043,648  dead after sampler
  u16*   accb  = (u16*)(ws + 66851840);     // 22,043,648  dead after out-proj
  u16*   xb    = (u16*)(ws + 720896);       // over value (dead)
  u16*   hb    = (u16*)(ws + 22764544);     // over offb (dead)

  u16* woffT  = wT;                // 256 rows; wattnT contiguous after (384-row B)
  u16* wvalT  = wT + 98304;
  u16* woutT  = wT + 163840;
  u16* w1T    = wT + 229376;
  u16* w2T    = wT + 294912;

  transpose_all_kernel<<<1408, 256, 0, stream>>>(w_off, w_attn, w_val, w_out, w1, w2, wT);

  const int gm = (LQ + 63) / 64;  // 673
  // value = query @ w_val + b_val (no pos)
  gemm_kernel<0, 1, 4><<<gm, 256, 0, stream>>>(query, wvalT, b_val, value, LQ);
  // offsets + softmaxed attention weights, A = bf16(query + pos)
  offaw_gemm_kernel<<<gm, 256, 0, stream>>>(query, pos, woffT, b_off, b_attn, offb, aw, LQ);
  // fused prep + sampling: 2 queries per block
  sampler_kernel<<<LQ / 2, 256, 0, stream>>>(refp, offb, aw, value, (u32*)accb);
  // x = LN(query + accb @ w_out + b_out) -> bf16
  gemm_ln_kernel<0, 1><<<gm, 256, 0, stream>>>(accb, woutT, b_out, query, g1, beta1, xb, LQ);
  // h = relu(x @ w1 + b1) -> bf16
  gemm_kernel<2, 2, 4><<<gm, 256, 0, stream>>>(xb, w1T, b1, hb, LQ);
  // out = LN(x + h @ w2 + b2) -> f32
  gemm_ln_kernel<1, 0><<<gm, 256, 0, stream>>>(hb, w2T, b2, xb, g2, beta2, d_out, LQ);
}

// Round 6
// 459.718 us; speedup vs baseline: 1.2332x; 1.2332x over previous
//
#include <hip/hip_runtime.h>

typedef unsigned short u16;
typedef unsigned int u32;
typedef float f32x4 __attribute__((ext_vector_type(4)));
typedef short i16x8 __attribute__((ext_vector_type(8)));
typedef __bf16 bf16x8_t __attribute__((ext_vector_type(8)));

#define LQ 43054

__device__ __forceinline__ float bf2f(u16 u) {
  union { u32 i; float f; } v; v.i = ((u32)u) << 16; return v.f;
}
__device__ __forceinline__ u16 f2bf(float f) {
  u32 i = __float_as_uint(f);
  return (u16)((i + 0x7FFFu + ((i >> 16) & 1u)) >> 16);
}

// ---- MFMA wrapper robust to builtin operand type (V8 short vs V8 __bf16) ----
template <typename T>
__device__ __forceinline__ auto mfma_try(T a, T b, f32x4 c, int)
    -> decltype(__builtin_amdgcn_mfma_f32_16x16x32_bf16(a, b, c, 0, 0, 0)) {
  return __builtin_amdgcn_mfma_f32_16x16x32_bf16(a, b, c, 0, 0, 0);
}
template <typename T>
__device__ __forceinline__ f32x4 mfma_try(T a, T b, f32x4 c, long) {
  return __builtin_amdgcn_mfma_f32_16x16x32_bf16(
      __builtin_bit_cast(bf16x8_t, a), __builtin_bit_cast(bf16x8_t, b), c, 0, 0, 0);
}
__device__ __forceinline__ f32x4 mfma_bf16(i16x8 a, i16x8 b, f32x4 c) {
  return mfma_try(a, b, c, 0);
}

// ---- all 6 weight transposes in one kernel: f32 (256 x N) -> bf16 (N x 256) ----
__global__ void transpose_all_kernel(
    const float* __restrict__ w_off, const float* __restrict__ w_attn,
    const float* __restrict__ w_val, const float* __restrict__ w_out,
    const float* __restrict__ w1, const float* __restrict__ w2,
    u16* __restrict__ wT) {
  int b = blockIdx.x;
  const float* src; u16* dst; int N; int col;
  if (b < 256)       { src = w_off;  dst = wT;          N = 256; col = b; }
  else if (b < 384)  { src = w_attn; dst = wT + 65536;  N = 128; col = b - 256; }
  else if (b < 640)  { src = w_val;  dst = wT + 98304;  N = 256; col = b - 384; }
  else if (b < 896)  { src = w_out;  dst = wT + 163840; N = 256; col = b - 640; }
  else if (b < 1152) { src = w1;     dst = wT + 229376; N = 256; col = b - 896; }
  else               { src = w2;     dst = wT + 294912; N = 256; col = b - 1152; }
  dst[col * 256 + threadIdx.x] = f2bf(src[threadIdx.x * N + col]);
}

// ================= shared helpers ==========================================
__device__ __forceinline__ void stage_a_bf16(uint4* As, const u16* A, int r0, int M, int tid) {
#pragma unroll
  for (int it = 0; it < 8; ++it) {
    int e = tid + it * 256;
    int row = e >> 5, c = e & 31;
    int gr = r0 + row;
    uint4 v = make_uint4(0u, 0u, 0u, 0u);
    if (gr < M) v = ((const uint4*)A)[gr * 32 + c];
    As[row * 32 + (c ^ (row & 7))] = v;
  }
}
template <int ADD>
__device__ __forceinline__ void stage_a_f32(uint4* As, const float* A, const float* A2,
                                            int r0, int M, int tid) {
#pragma unroll
  for (int it = 0; it < 16; ++it) {
    int e = tid + it * 256;
    int row = e >> 6, c4 = e & 63;
    int gr = r0 + row;
    float4 v = make_float4(0.f, 0.f, 0.f, 0.f);
    if (gr < M) {
      v = ((const float4*)A)[gr * 64 + c4];
      if constexpr (ADD) {
        float4 p = ((const float4*)A2)[gr * 64 + c4];
        v.x += p.x; v.y += p.y; v.z += p.z; v.w += p.w;
      }
    }
    uint2 pk;
    pk.x = (u32)f2bf(v.x) | ((u32)f2bf(v.y) << 16);
    pk.y = (u32)f2bf(v.z) | ((u32)f2bf(v.w) << 16);
    int c = c4 >> 1, hf = c4 & 1;
    ((uint2*)As)[((row * 32 + (c ^ (row & 7))) << 1) | hf] = pk;
  }
}
// load one 16-col B tile's 8 K-fragments into registers
__device__ __forceinline__ void load_b(i16x8* f, const u16* Bt, int t, int l16, int quad) {
  const uint4* bp = (const uint4*)Bt + (t * 16 + l16) * 32 + quad;
#pragma unroll
  for (int kk = 0; kk < 8; ++kk) f[kk] = __builtin_bit_cast(i16x8, bp[kk << 2]);
}
// 32 MFMAs of one tile over all 4 row-groups, A from LDS
__device__ __forceinline__ void tile_mfma(f32x4* acc, const uint4* As,
                                          const i16x8* bfr, int l16, int quad) {
#pragma unroll
  for (int rg = 0; rg < 4; ++rg) {
    int arow = rg * 16 + l16;
    f32x4 a = {0.f, 0.f, 0.f, 0.f};
#pragma unroll
    for (int kk = 0; kk < 8; ++kk) {
      i16x8 afr = __builtin_bit_cast(i16x8, As[arow * 32 + (((kk << 2) + quad) ^ (arow & 7))]);
      a = mfma_bf16(afr, bfr[kk], a);
    }
    acc[rg] = a;
  }
}

// ---- generic GEMM: wave owns TILES/4 col-tiles, sweeps all 64 rows ----
// AIN: 0 = A f32, 2 = A bf16.  MODE: 1 = bf16, 2 = relu+bf16.  NT = N/64.
template <int AIN, int MODE, int NT>
__global__ __launch_bounds__(256, 3) void gemm_kernel(
    const void* __restrict__ Av, const u16* __restrict__ Bt,
    const float* __restrict__ bias, void* __restrict__ out, int M) {
  constexpr int N = NT * 64;
  constexpr int TPW = NT;  // (NT*4 tiles)/4 waves
  __shared__ uint4 As[2048];
  const int tid = threadIdx.x;
  const int w = tid >> 6, lane = tid & 63, quad = lane >> 4, l16 = lane & 15;
  const int r0 = blockIdx.x * 64;
  if constexpr (AIN == 2) stage_a_bf16(As, (const u16*)Av, r0, M, tid);
  else                    stage_a_f32<0>(As, (const float*)Av, nullptr, r0, M, tid);
  __syncthreads();
  i16x8 bfr[2][8];
  load_b(bfr[0], Bt, w * TPW, l16, quad);
#pragma unroll
  for (int i = 0; i < TPW; ++i) {
    const int t = w * TPW + i;
    if (i + 1 < TPW) load_b(bfr[(i + 1) & 1], Bt, t + 1, l16, quad);
    f32x4 acc[4];
    tile_mfma(acc, As, bfr[i & 1], l16, quad);
    const int col = t * 16 + l16;
    const float bv = bias[col];
#pragma unroll
    for (int rg = 0; rg < 4; ++rg)
#pragma unroll
      for (int r = 0; r < 4; ++r) {
        int row = r0 + rg * 16 + (quad << 2) + r;
        if (row < M) {
          float val = acc[rg][r] + bv;
          if (MODE == 1) ((u16*)out)[row * N + col] = f2bf(val);
          else           ((u16*)out)[row * N + col] = f2bf(fmaxf(val, 0.f));
        }
      }
  }
}

// ---- fused offsets + attention-softmax GEMM: A = bf16(query + pos) ----
// 24 tiles, 6 per wave. Tiles 0..15 -> offb bf16; 16..23 -> softmax -> aw f32.
__global__ __launch_bounds__(256, 3) void offaw_gemm_kernel(
    const float* __restrict__ query, const float* __restrict__ pos,
    const u16* __restrict__ Bt, const float* __restrict__ b_off,
    const float* __restrict__ b_attn, u16* __restrict__ offb,
    float* __restrict__ aw, int M) {
  __shared__ uint4 As[2048];
  const int tid = threadIdx.x;
  const int w = tid >> 6, lane = tid & 63, quad = lane >> 4, l16 = lane & 15;
  const int r0 = blockIdx.x * 64;
  stage_a_f32<1>(As, query, pos, r0, M, tid);
  __syncthreads();
  i16x8 bfr[2][8];
  load_b(bfr[0], Bt, w * 6, l16, quad);
#pragma unroll
  for (int i = 0; i < 6; ++i) {
    const int t = w * 6 + i;
    if (i + 1 < 6) load_b(bfr[(i + 1) & 1], Bt, t + 1, l16, quad);
    f32x4 acc[4];
    tile_mfma(acc, As, bfr[i & 1], l16, quad);
    if (t < 16) {
      const int col = t * 16 + l16;
      const float bv = b_off[col];
#pragma unroll
      for (int rg = 0; rg < 4; ++rg)
#pragma unroll
        for (int r = 0; r < 4; ++r) {
          int row = r0 + rg * 16 + (quad << 2) + r;
          if (row < M) ((u16*)offb)[row * 256 + col] = f2bf(acc[rg][r] + bv);
        }
    } else {
      const int colc = (t - 16) * 16 + l16;
      const float bv = b_attn[colc];
#pragma unroll
      for (int rg = 0; rg < 4; ++rg)
#pragma unroll
        for (int r = 0; r < 4; ++r) {
          float v = acc[rg][r] + bv;
          float m = v;
#pragma unroll
          for (int o = 1; o < 16; o <<= 1) m = fmaxf(m, __shfl_xor(m, o));
          float e = __expf(v - m);
          float s = e;
#pragma unroll
          for (int o = 1; o < 16; o <<= 1) s += __shfl_xor(s, o);
          int row = r0 + rg * 16 + (quad << 2) + r;
          if (row < M) aw[row * 128 + colc] = e / s;
        }
    }
  }
}

// ---- GEMM + residual + LayerNorm; cross-wave LN partials through LDS ----
// RBF: resid bf16 if 1 else f32.  OBF: out bf16 if 1 else f32.
template <int RBF, int OBF>
__global__ __launch_bounds__(256, 2) void gemm_ln_kernel(
    const u16* __restrict__ A, const u16* __restrict__ Bt,
    const float* __restrict__ bias, const void* __restrict__ residv,
    const float* __restrict__ g, const float* __restrict__ beta,
    void* __restrict__ outv, int M) {
  __shared__ uint4 As[2048];
  __shared__ float2 pnorm[256];  // [row][wave] partial {s, s2}
  const int tid = threadIdx.x;
  const int w = tid >> 6, lane = tid & 63, quad = lane >> 4, l16 = lane & 15;
  const int r0 = blockIdx.x * 64;
  stage_a_bf16(As, A, r0, M, tid);
  __syncthreads();
  i16x8 bfr[2][8];
  load_b(bfr[0], Bt, w * 4, l16, quad);
  f32x4 vals[4][4];  // [tile][rg]
#pragma unroll
  for (int i = 0; i < 4; ++i) {
    const int t = w * 4 + i;
    if (i + 1 < 4) load_b(bfr[(i + 1) & 1], Bt, t + 1, l16, quad);
    tile_mfma(vals[i], As, bfr[i & 1], l16, quad);
  }
  // bias + residual + stats
  float s[16], s2[16];
#pragma unroll
  for (int k = 0; k < 16; ++k) { s[k] = 0.f; s2[k] = 0.f; }
#pragma unroll
  for (int i = 0; i < 4; ++i) {
    const int col = (w * 4 + i) * 16 + l16;
    const float bv = bias[col];
#pragma unroll
    for (int rg = 0; rg < 4; ++rg)
#pragma unroll
      for (int r = 0; r < 4; ++r) {
        int row = r0 + rg * 16 + (quad << 2) + r;
        float rv = 0.f;
        if (row < M) rv = RBF ? bf2f(((const u16*)residv)[row * 256 + col])
                              : ((const float*)residv)[row * 256 + col];
        float v = vals[i][rg][r] + bv + rv;
        vals[i][rg][r] = v;
        s[rg * 4 + r] += v; s2[rg * 4 + r] += v * v;
      }
  }
  // reduce over the 16 l16 lanes (this wave's 64 cols), publish partials
#pragma unroll
  for (int k = 0; k < 16; ++k)
#pragma unroll
    for (int o = 1; o < 16; o <<= 1) {
      s[k] += __shfl_xor(s[k], o);
      s2[k] += __shfl_xor(s2[k], o);
    }
  if (l16 == 0) {
#pragma unroll
    for (int rg = 0; rg < 4; ++rg)
#pragma unroll
      for (int r = 0; r < 4; ++r) {
        int lrow = rg * 16 + (quad << 2) + r;
        pnorm[lrow * 4 + w] = make_float2(s[rg * 4 + r], s2[rg * 4 + r]);
      }
  }
  __syncthreads();
  // combine 4 wave-partials, normalize, store
#pragma unroll
  for (int rg = 0; rg < 4; ++rg)
#pragma unroll
    for (int r = 0; r < 4; ++r) {
      int lrow = rg * 16 + (quad << 2) + r;
      float4 p01 = ((const float4*)pnorm)[lrow * 2];
      float4 p23 = ((const float4*)pnorm)[lrow * 2 + 1];
      float ss = p01.x + p01.z + p23.x + p23.z;
      float qq = p01.y + p01.w + p23.y + p23.w;
      float mean = ss * (1.f / 256.f);
      float var = qq * (1.f / 256.f) - mean * mean;
      float inv = rsqrtf(var + 1e-5f);
      int row = r0 + lrow;
      if (row < M) {
#pragma unroll
        for (int i = 0; i < 4; ++i) {
          const int col = (w * 4 + i) * 16 + l16;
          float o = (vals[i][rg][r] - mean) * inv * g[col] + beta[col];
          if (OBF) ((u16*)outv)[row * 256 + col] = f2bf(o);
          else     ((float*)outv)[row * 256 + col] = o;
        }
      }
    }
}

// ---- fused prep + deformable sampling: one block = 2 queries (unchanged) ----
__global__ __launch_bounds__(256) void sampler_kernel(
    const float* __restrict__ refp, const u16* __restrict__ offb,
    const float* __restrict__ aw, const u16* __restrict__ value,
    u32* __restrict__ accv) {
  __shared__ uint4 rec[272];
  const int t = threadIdx.x;
  const int b = blockIdx.x;
  {
    const int qs = t >> 7, j = t & 127;
    const int i = b * 2 + qs;
    const int h = j >> 4, lp = j & 15, l = lp >> 2;
    const int Wl = (l == 0) ? 180 : (l == 1) ? 90 : (l == 2) ? 45 : 23;
    const int st = (l == 0) ? 0 : (l == 1) ? 32400 : (l == 2) ? 40500 : 42525;
    const float wj = aw[i * 128 + j];
    const u32 o2 = *(const u32*)(offb + i * 256 + h * 32 + lp * 2);
    const float ox = bf2f((u16)(o2 & 0xffffu)), oy = bf2f((u16)(o2 >> 16));
    const float rx = refp[i * 8 + l * 2], ry = refp[i * 8 + l * 2 + 1];
    float x = rx * (float)Wl + ox - 0.5f;
    float y = ry * (float)Wl + oy - 0.5f;
    float x0f = floorf(x), y0f = floorf(y);
    float fx = x - x0f, fy = y - y0f;
    int x0 = (int)x0f, y0 = (int)y0f;
    bool vx0 = (x0 >= 0) & (x0 < Wl), vx1 = (x0 + 1 >= 0) & (x0 + 1 < Wl);
    bool vy0 = (y0 >= 0) & (y0 < Wl), vy1 = (y0 + 1 >= 0) & (y0 + 1 < Wl);
    int x0c = min(max(x0, 0), Wl - 1), x1c = min(max(x0 + 1, 0), Wl - 1);
    int y0c = min(max(y0, 0), Wl - 1), y1c = min(max(y0 + 1, 0), Wl - 1);
    float w00 = (vx0 & vy0) ? wj * (1.f - fx) * (1.f - fy) : 0.f;
    float w01 = (vx1 & vy0) ? wj * fx * (1.f - fy) : 0.f;
    float w10 = (vx0 & vy1) ? wj * (1.f - fx) * fy : 0.f;
    float w11 = (vx1 & vy1) ? wj * fx * fy : 0.f;
    uint4 r;
    r.x = (u32)((st + y0c * Wl + x0c) * 512 + h * 64) | (u32)(x1c - x0c);
    r.y = (u32)(y1c - y0c) * (u32)(Wl * 512);
    r.z = (u32)f2bf(w00) | ((u32)f2bf(w01) << 16);
    r.w = (u32)f2bf(w10) | ((u32)f2bf(w11) << 16);
    rec[qs * 136 + h * 17 + lp] = r;
  }
  __syncthreads();
  const int qs = t >> 7, j = t & 127;
  const int h = j >> 4, dp = j & 15;
  const char* vb = (const char*)value;
  float a0 = 0.f, a1 = 0.f;
  const int rbase = qs * 136 + h * 17;
#pragma unroll
  for (int p = 0; p < 16; ++p) {
    uint4 r = rec[rbase + p];
    u32 base = (r.x & 0xFFFFFFFEu) + (u32)(dp * 4);
    u32 dxo = (r.x & 1u) << 9;
    u32 dyo = r.y;
    float w00 = __uint_as_float(r.z << 16);
    float w01 = __uint_as_float(r.z & 0xFFFF0000u);
    float w10 = __uint_as_float(r.w << 16);
    float w11 = __uint_as_float(r.w & 0xFFFF0000u);
    u32 p00 = *(const u32*)(vb + base);
    u32 p01 = *(const u32*)(vb + base + dxo);
    u32 p10 = *(const u32*)(vb + base + dyo);
    u32 p11 = *(const u32*)(vb + base + dyo + dxo);
    a0 = fmaf(w00, __uint_as_float(p00 << 16), a0);
    a1 = fmaf(w00, __uint_as_float(p00 & 0xFFFF0000u), a1);
    a0 = fmaf(w01, __uint_as_float(p01 << 16), a0);
    a1 = fmaf(w01, __uint_as_float(p01 & 0xFFFF0000u), a1);
    a0 = fmaf(w10, __uint_as_float(p10 << 16), a0);
    a1 = fmaf(w10, __uint_as_float(p10 & 0xFFFF0000u), a1);
    a0 = fmaf(w11, __uint_as_float(p11 << 16), a0);
    a1 = fmaf(w11, __uint_as_float(p11 & 0xFFFF0000u), a1);
  }
  u32 pk = (u32)f2bf(a0) | ((u32)f2bf(a1) << 16);
  accv[(b * 2 + qs) * 128 + j] = pk;
}

extern "C" void kernel_launch(void* const* d_in, const int* in_sizes, int n_in,
                              void* d_out, int out_size, void* d_ws, size_t ws_size,
                              hipStream_t stream) {
  const float* query  = (const float*)d_in[0];
  const float* refp   = (const float*)d_in[1];
  const float* pos    = (const float*)d_in[2];
  const float* w_off  = (const float*)d_in[5];
  const float* b_off  = (const float*)d_in[6];
  const float* w_attn = (const float*)d_in[7];
  const float* b_attn = (const float*)d_in[8];
  const float* w_val  = (const float*)d_in[9];
  const float* b_val  = (const float*)d_in[10];
  const float* w_out  = (const float*)d_in[11];
  const float* b_out  = (const float*)d_in[12];
  const float* g1     = (const float*)d_in[13];
  const float* beta1  = (const float*)d_in[14];
  const float* w1     = (const float*)d_in[15];
  const float* b1     = (const float*)d_in[16];
  const float* w2     = (const float*)d_in[17];
  const float* b2     = (const float*)d_in[18];
  const float* g2     = (const float*)d_in[19];
  const float* beta2  = (const float*)d_in[20];

  char* ws = (char*)d_ws;
  u16*   wT    = (u16*)(ws + 0);            //   720,896, live whole launch
  u16*   value = (u16*)(ws + 720896);       // 22,043,648  dead after sampler
  u16*   offb  = (u16*)(ws + 22764544);     // 22,043,648  dead after sampler
  float* aw    = (float*)(ws + 44808192);   // 22,043,648  dead after sampler
  u16*   accb  = (u16*)(ws + 66851840);     // 22,043,648  dead after out-proj
  u16*   xb    = (u16*)(ws + 720896);       // over value (dead)
  u16*   hb    = (u16*)(ws + 22764544);     // over offb (dead)

  u16* woffT  = wT;                // 256 rows; wattnT contiguous after (384-row B)
  u16* wvalT  = wT + 98304;
  u16* woutT  = wT + 163840;
  u16* w1T    = wT + 229376;
  u16* w2T    = wT + 294912;

  transpose_all_kernel<<<1408, 256, 0, stream>>>(w_off, w_attn, w_val, w_out, w1, w2, wT);

  const int gm = (LQ + 63) / 64;  // 673
  gemm_kernel<0, 1, 4><<<gm, 256, 0, stream>>>(query, wvalT, b_val, value, LQ);
  offaw_gemm_kernel<<<gm, 256, 0, stream>>>(query, pos, woffT, b_off, b_attn, offb, aw, LQ);
  sampler_kernel<<<LQ / 2, 256, 0, stream>>>(refp, offb, aw, value, (u32*)accb);
  gemm_ln_kernel<0, 1><<<gm, 256, 0, stream>>>(accb, woutT, b_out, query, g1, beta1, xb, LQ);
  gemm_kernel<2, 2, 4><<<gm, 256, 0, stream>>>(xb, w1T, b1, hb, LQ);
  gemm_ln_kernel<1, 0><<<gm, 256, 0, stream>>>(hb, w2T, b2, xb, g2, beta2, d_out, LQ);
}